// Round 19
// baseline (152.455 us; speedup 1.0000x reference)
//
#include <hip/hip_runtime.h>

#define B_ 4
#define T_ 2048
#define D_ 1024
#define H_ 16
#define BT_ (B_ * T_)
#define QSCALE (0.125f * 1.44269504088896f)   // 1/sqrt(64) * log2(e), exp2-domain softmax

typedef unsigned short u16;
typedef unsigned long long u64;
typedef __attribute__((ext_vector_type(8))) __bf16 bf16x8;
typedef __attribute__((ext_vector_type(4))) float f32x4;
typedef __attribute__((ext_vector_type(16))) float f32x16;

__device__ __forceinline__ u16 f2bf(float f) {      // f32 -> bf16 RNE
  unsigned u = __builtin_bit_cast(unsigned, f);
  u += 0x7FFFu + ((u >> 16) & 1u);
  return (u16)(u >> 16);
}

__device__ __forceinline__ void gload16(const void* g, void* l) {
  __builtin_amdgcn_global_load_lds(
      (const __attribute__((address_space(1))) void*)g,
      (__attribute__((address_space(3))) void*)l, 16, 0, 0);
}

// ---------------- fused converts: x + 4 weights + padding tile-flags ----------------
__global__ void cvt_all(const float* __restrict__ x,
                        const float* __restrict__ Wq, const float* __restrict__ Wk,
                        const float* __restrict__ Wv, const float* __restrict__ Wo,
                        u16* __restrict__ xb, u16* __restrict__ wdst,
                        const unsigned char* __restrict__ pm, unsigned char* __restrict__ fl) {
  const int fb = blockIdx.x;
  if (fb < 8192) {                                  // x: BT*D/4 float4s
    const int i = fb * 256 + threadIdx.x;
    const float4 v = ((const float4*)x)[i];
    ushort4 o;
    o.x = f2bf(v.x); o.y = f2bf(v.y); o.z = f2bf(v.z); o.w = f2bf(v.w);
    ((ushort4*)xb)[i] = o;
  } else if (fb < 12288) {                          // weights: 4 x D*D/4
    const int wsel = (fb - 8192) >> 10;
    const float* src = (wsel == 0) ? Wq : (wsel == 1) ? Wk : (wsel == 2) ? Wv : Wo;
    const int i = ((fb - 8192) & 1023) * 256 + threadIdx.x;
    const float4 v = ((const float4*)src)[i];
    ushort4 o;
    o.x = f2bf(v.x); o.y = f2bf(v.y); o.z = f2bf(v.z); o.w = f2bf(v.w);
    ((ushort4*)(wdst + (size_t)wsel * D_ * D_))[i] = o;
  } else if (threadIdx.x < 128) {                   // per-64-token padding flags
    const int i = threadIdx.x;
    const u64* p = (const u64*)(pm + i * 64);
    u64 acc = 0;
#pragma unroll
    for (int k = 0; k < 8; ++k) acc |= p[k];
    fl[i] = acc ? 1 : 0;
  }
}

// ---------------- GEMM: 128x128 tile, BK=64, 4 waves, swizzled LDS ----------------
// NEW: 32x32x16 MFMA (same 64x64 wave-tile, 16 MFMA issues/K-tile instead of 32;
// ds_read count unchanged; kernel is issue-bound per m98 so shorter stream wins).
// A-op row=lane&31 k=(lane>>5)*8+e; B-op col=lane&31 same k;
// C/D col=lane&31, row=(reg&3)+8*(reg>>2)+4*(lane>>5)  [guide m74/m101].
// MODE 1: fused QKV -> Cq (x QSCALE), Ck, Cvt (transposed); MODE 0: out-proj.
template<int MODE>
__global__ __launch_bounds__(256, 2) void gemm_bt(
    const u16* __restrict__ A, const u16* __restrict__ Bw,
    float* __restrict__ Cf, const float* __restrict__ bias,
    const unsigned char* __restrict__ rowmask,
    u16* __restrict__ Cq, u16* __restrict__ Ck, u16* __restrict__ Cvt)
{
  __shared__ __align__(16) u16 sA[128 * 64];
  __shared__ __align__(16) u16 sB[128 * 64];
  const int tid = threadIdx.x;
  const int lane = tid & 63, wave = tid >> 6;
  const int l31 = lane & 31, hl = lane >> 5;
  const int bm = blockIdx.x * 128, bn = blockIdx.y * 128;
  const int wr = wave >> 1, wc = wave & 1;

  const int srow = lane >> 3;
  const int scol = ((lane & 7) ^ srow) << 3;

  f32x16 acc[2][2] = {};

  for (int kt = 0; kt < 16; ++kt) {
    __syncthreads();
    const int k0 = kt << 6;
#pragma unroll
    for (int c = 0; c < 4; ++c) {
      const int chunk = c * 4 + wave;
      gload16(A  + (size_t)(bm + chunk * 8 + srow) * 1024 + k0 + scol, (char*)sA + chunk * 1024);
      gload16(Bw + (size_t)(bn + chunk * 8 + srow) * 1024 + k0 + scol, (char*)sB + chunk * 1024);
    }
    __syncthreads();
#pragma unroll
    for (int ks = 0; ks < 4; ++ks) {                     // K=64 in 4 steps of 16
      const int cb = (((ks * 2 + hl) ^ (l31 & 7)) << 4); // chunk ^ row-swizzle
      bf16x8 af[2], bf[2];
#pragma unroll
      for (int m = 0; m < 2; ++m)
        af[m] = *(const bf16x8*)((const char*)sA + (wr * 64 + m * 32 + l31) * 128 + cb);
#pragma unroll
      for (int n = 0; n < 2; ++n)
        bf[n] = *(const bf16x8*)((const char*)sB + (wc * 64 + n * 32 + l31) * 128 + cb);
#pragma unroll
      for (int m = 0; m < 2; ++m)
#pragma unroll
        for (int n = 0; n < 2; ++n)
          acc[m][n] = __builtin_amdgcn_mfma_f32_32x32x16_bf16(af[m], bf[n], acc[m][n], 0, 0, 0);
    }
  }

  if (MODE == 1) {
    const int region = bn >> 10;               // 0=Q 1=K 2=V (block-uniform)
    const float a = (region == 0) ? QSCALE : 1.f;
#pragma unroll
    for (int m = 0; m < 2; ++m)
#pragma unroll
      for (int n = 0; n < 2; ++n) {
        const int col = bn + wc * 64 + n * 32 + l31;
        const int colr = col & 1023;
#pragma unroll
        for (int rg = 0; rg < 4; ++rg) {
          const int row0 = bm + wr * 64 + m * 32 + rg * 8 + hl * 4;
          if (region == 2) {
            ushort4 w;
            w.x = f2bf(acc[m][n][rg * 4 + 0]); w.y = f2bf(acc[m][n][rg * 4 + 1]);
            w.z = f2bf(acc[m][n][rg * 4 + 2]); w.w = f2bf(acc[m][n][rg * 4 + 3]);
            *(ushort4*)(Cvt + (size_t)colr * BT_ + row0) = w;   // V^T[d][token]
          } else {
            u16* dst = region ? Ck : Cq;
#pragma unroll
            for (int r = 0; r < 4; ++r)
              dst[(size_t)(row0 + r) * 1024 + colr] = f2bf(acc[m][n][rg * 4 + r] * a);
          }
        }
      }
  } else {
#pragma unroll
    for (int m = 0; m < 2; ++m)
#pragma unroll
      for (int n = 0; n < 2; ++n) {
        const int col = bn + wc * 64 + n * 32 + l31;
        const float bv = bias[col];
#pragma unroll
        for (int rg = 0; rg < 4; ++rg) {
          const int row0 = bm + wr * 64 + m * 32 + rg * 8 + hl * 4;
#pragma unroll
          for (int r = 0; r < 4; ++r) {
            float v = acc[m][n][rg * 4 + r] + bv;
            v = rowmask[row0 + r] ? 0.f : v;
            Cf[(size_t)(row0 + r) * 1024 + col] = v;
          }
        }
      }
  }
}

// ---------------- Flash attention (causal), O^T = V^T @ P^T, P in registers ----------
// (proven r15 structure: 8 waves x 16 q-rows, sequential (j,15-j) halves,
// T15 cross-tile pipeline, 4-slot KV ring, counted vmcnt, static-shift softmax)
#define QK_TILE(T, ST) do {                                                    \
  const int kvq_ = (T) << 6;                                                   \
  _Pragma("unroll")                                                            \
  for (int jf_ = 0; jf_ < 4; ++jf_) ST[jf_] = f32x4{};                         \
  if (kvq_ <= qw + 15) {                                                       \
    const u16* kbq_ = &sK[(T) & 3][0];                                         \
    _Pragma("unroll")                                                          \
    for (int ks_ = 0; ks_ < 2; ++ks_) {                                        \
      bf16x8 kf_[4];                                                           \
      _Pragma("unroll")                                                        \
      for (int jf_ = 0; jf_ < 4; ++jf_)                                        \
        kf_[jf_] = *(const bf16x8*)(kbq_ + (jf_ * 16 + s15) * 64 +             \
                                    (((ks_ * 4 + g) ^ (s15 & 7)) << 3));       \
      __builtin_amdgcn_s_setprio(1);                                           \
      _Pragma("unroll")                                                        \
      for (int jf_ = 0; jf_ < 4; ++jf_)                                        \
        ST[jf_] = __builtin_amdgcn_mfma_f32_16x16x32_bf16(kf_[jf_], qf[ks_],   \
                                                          ST[jf_], 0, 0, 0);   \
      __builtin_amdgcn_s_setprio(0);                                           \
    }                                                                          \
  }                                                                            \
} while (0)

#define ATTN_ITER(T, CUR, NXT) do {                                            \
  const int kv0_ = (T) << 6;                                                   \
  if ((T) + 3 < nt) {                                                          \
    const int s_ = ((T) + 3) & 3;                                              \
    gload16(Kb0 + (size_t)(kv0_ + 192 + srow) * D_, (char*)(&sK[s_][0]) + tid * 16); \
    gload16(Vb0 + (size_t)srow * BT_ + kv0_ + 192,  (char*)(&sV[s_][0]) + tid * 16); \
  }                                                                            \
  if ((T) + 1 < nt) QK_TILE((T) + 1, NXT);                                     \
  if (kv0_ <= qw + 15) {                                                       \
    if (kv0_ + 63 > qw) {                                                      \
      const int iq_ = qw + s15;                                                \
      _Pragma("unroll")                                                        \
      for (int jf_ = 0; jf_ < 4; ++jf_) {                                      \
        const int jb_ = kv0_ + jf_ * 16 + g * 4;                               \
        _Pragma("unroll")                                                      \
        for (int r_ = 0; r_ < 4; ++r_)                                         \
          if (jb_ + r_ > iq_) CUR[jf_][r_] = -1e30f;                           \
      }                                                                        \
    }                                                                          \
    if ((flq[(T) >> 3] >> (((T) & 7) * 8)) & 0xff) {                           \
      _Pragma("unroll")                                                        \
      for (int jf_ = 0; jf_ < 4; ++jf_) {                                      \
        const int jb_ = kv0_ + jf_ * 16 + g * 4;                               \
        uchar4 p4_ = *(const uchar4*)(pm + b * T_ + jb_);                      \
        const unsigned char* pr_ = (const unsigned char*)&p4_;                 \
        _Pragma("unroll")                                                      \
        for (int r_ = 0; r_ < 4; ++r_)                                         \
          if (pr_[r_]) CUR[jf_][r_] = -1e30f;                                  \
      }                                                                        \
    }                                                                          \
    _Pragma("unroll")                                                          \
    for (int jf_ = 0; jf_ < 4; ++jf_) {                                        \
      _Pragma("unroll")                                                        \
      for (int r_ = 0; r_ < 4; ++r_)                                           \
        CUR[jf_][r_] = __builtin_amdgcn_exp2f(CUR[jf_][r_]);                   \
      l4 += CUR[jf_];                                                          \
    }                                                                          \
    const u16* vbq_ = &sV[(T) & 3][0];                                         \
    _Pragma("unroll")                                                          \
    for (int kb_ = 0; kb_ < 2; ++kb_) {                                        \
      bf16x8 vf_[4];                                                           \
      _Pragma("unroll")                                                        \
      for (int df_ = 0; df_ < 4; ++df_)                                        \
        vf_[df_] = *(const bf16x8*)(vbq_ + (df_ * 16 + s15) * 64 +             \
                                    (((kb_ * 4 + g) ^ (s15 & 7)) << 3));       \
      unsigned w00, w01, w10, w11;                                             \
      asm("v_cvt_pk_bf16_f32 %0, %1, %2" : "=v"(w00) : "v"(CUR[2*kb_][0]),   "v"(CUR[2*kb_][1]));   \
      asm("v_cvt_pk_bf16_f32 %0, %1, %2" : "=v"(w01) : "v"(CUR[2*kb_][2]),   "v"(CUR[2*kb_][3]));   \
      asm("v_cvt_pk_bf16_f32 %0, %1, %2" : "=v"(w10) : "v"(CUR[2*kb_+1][0]), "v"(CUR[2*kb_+1][1])); \
      asm("v_cvt_pk_bf16_f32 %0, %1, %2" : "=v"(w11) : "v"(CUR[2*kb_+1][2]), "v"(CUR[2*kb_+1][3])); \
      asm("v_permlane32_swap_b32 %0, %1" : "+v"(w00), "+v"(w10));              \
      asm("v_permlane16_swap_b32 %0, %1" : "+v"(w00), "+v"(w10));              \
      asm("v_permlane32_swap_b32 %0, %1" : "+v"(w01), "+v"(w11));              \
      asm("v_permlane16_swap_b32 %0, %1" : "+v"(w01), "+v"(w11));              \
      union { unsigned u[4]; bf16x8 v; } pf_;                                  \
      pf_.u[0] = w00; pf_.u[1] = w01; pf_.u[2] = w10; pf_.u[3] = w11;          \
      __builtin_amdgcn_s_setprio(1);                                           \
      _Pragma("unroll")                                                        \
      for (int df_ = 0; df_ < 4; ++df_)                                        \
        o[df_] = __builtin_amdgcn_mfma_f32_16x16x32_bf16(vf_[df_], pf_.v,      \
                                                         o[df_], 0, 0, 0);     \
      __builtin_amdgcn_s_setprio(0);                                           \
    }                                                                          \
  }                                                                            \
  if ((T) + 1 < nt) {                                                          \
    if ((T) + 3 < nt) asm volatile("s_waitcnt vmcnt(2) lgkmcnt(0)" ::: "memory"); \
    else              asm volatile("s_waitcnt vmcnt(0) lgkmcnt(0)" ::: "memory"); \
    __builtin_amdgcn_s_barrier();                                              \
    asm volatile("" ::: "memory");                                             \
  }                                                                            \
} while (0)

__global__ __launch_bounds__(512, 4) void attn_fwd(
    const u16* __restrict__ Q, const u16* __restrict__ K,
    const u16* __restrict__ VT, const unsigned char* __restrict__ pm,
    const unsigned char* __restrict__ tileflag, u16* __restrict__ O)
{
  __shared__ __align__(16) u16 sK[4][64 * 64];   // 32 KB
  __shared__ __align__(16) u16 sV[4][64 * 64];   // 32 KB
  const int tid = threadIdx.x;
  const int lane = tid & 63, wave = tid >> 6;      // 8 waves
  const int g = lane >> 4, s15 = lane & 15;
  const int bh = blockIdx.x, b = bh >> 4, h = bh & 15;
  const int jpair = blockIdx.y;                    // 0..7
  const size_t tokbase = (size_t)b * T_;

  const int srow = tid >> 3;                       // staging: row 0..63, 16B chunk
  const int sc = (tid & 7) ^ (srow & 7);
  const u16* Kb0 = K + tokbase * D_ + h * 64 + sc * 8;
  const u16* Vb0 = VT + (size_t)(h * 64) * BT_ + tokbase + sc * 8;

  u64 flq[4];
#pragma unroll
  for (int q = 0; q < 4; ++q) flq[q] = ((const u64*)(tileflag + b * 32))[q];

#pragma unroll
  for (int half = 0; half < 2; ++half) {
    const int qt = half ? (15 - jpair) : jpair;
    const int qw = qt * 128 + wave * 16;
    const int nt = 2 * qt + 2;                     // even, >= 2

    bf16x8 qf[2];
#pragma unroll
    for (int ks = 0; ks < 2; ++ks)
      qf[ks] = *(const bf16x8*)(Q + (tokbase + qw + s15) * D_ + h * 64 + ks * 32 + g * 8);

    f32x4 o[4] = {};
    f32x4 l4 = {};

    __syncthreads();
#pragma unroll
    for (int s = 0; s < 3; ++s) {
      gload16(Kb0 + (size_t)(s * 64 + srow) * D_, (char*)(&sK[s][0]) + tid * 16);
      gload16(Vb0 + (size_t)srow * BT_ + s * 64,  (char*)(&sV[s][0]) + tid * 16);
    }
    asm volatile("s_waitcnt vmcnt(2) lgkmcnt(0)" ::: "memory");
    __builtin_amdgcn_s_barrier();
    asm volatile("" ::: "memory");

    f32x4 stA[4], stB[4];
    QK_TILE(0, stA);

    for (int t = 0; t < nt; t += 2) {
      ATTN_ITER(t, stA, stB);
      ATTN_ITER(t + 1, stB, stA);
    }

    float lv = (l4[0] + l4[1]) + (l4[2] + l4[3]);
    lv += __shfl_xor(lv, 16);
    lv += __shfl_xor(lv, 32);
    const float inv = 1.f / lv;
    u16* orow = O + (tokbase + qw + s15) * D_ + h * 64 + g * 4;
#pragma unroll
    for (int df = 0; df < 4; ++df) {
      ushort4 w;
      w.x = f2bf(o[df][0] * inv); w.y = f2bf(o[df][1] * inv);
      w.z = f2bf(o[df][2] * inv); w.w = f2bf(o[df][3] * inv);
      *(ushort4*)(orow + df * 16) = w;
    }
  }
}

// ---------------- launcher ----------------
extern "C" void kernel_launch(void* const* d_in, const int* in_sizes, int n_in,
                              void* d_out, int out_size, void* d_ws, size_t ws_size,
                              hipStream_t stream)
{
  const float* x  = (const float*)d_in[0];
  const unsigned char* pm = (const unsigned char*)d_in[1];
  const float* Wq = (const float*)d_in[2];
  const float* Wk = (const float*)d_in[3];
  const float* Wv = (const float*)d_in[4];
  const float* Wo = (const float*)d_in[5];
  const float* bo = (const float*)d_in[6];
  float* out = (float*)d_out;

  char* w = (char*)d_ws;
  u16* xb  = (u16*)w; w += (size_t)BT_ * D_ * 2;
  u16* wqb = (u16*)w; w += (size_t)D_ * D_ * 2;   // wq|wk|wv|wo contiguous
  u16* wkb = (u16*)w; w += (size_t)D_ * D_ * 2;
  u16* wvb = (u16*)w; w += (size_t)D_ * D_ * 2;
  u16* wob = (u16*)w; w += (size_t)D_ * D_ * 2;
  u16* qb  = (u16*)w; w += (size_t)BT_ * D_ * 2;
  u16* kbf = (u16*)w; w += (size_t)BT_ * D_ * 2;
  u16* vt  = (u16*)w; w += (size_t)BT_ * D_ * 2;  // V^T [1024][8192]
  u16* ao  = (u16*)w; w += (size_t)BT_ * D_ * 2;
  unsigned char* flags = (unsigned char*)w; w += 256;
  (void)wkb; (void)wvb;

  cvt_all<<<12289, 256, 0, stream>>>(x, Wq, Wk, Wv, Wo, xb, wqb, pm, flags);

  gemm_bt<1><<<dim3(64, 24), 256, 0, stream>>>(xb, wqb, nullptr, nullptr, nullptr, qb, kbf, vt);

  attn_fwd<<<dim3(B_ * H_, 8), 512, 0, stream>>>(qb, kbf, vt, pm, flags, ao);

  gemm_bt<0><<<dim3(64, 8), 256, 0, stream>>>(ao, wob, out, bo, pm, nullptr, nullptr, nullptr);
}

// Round 20
// 141.112 us; speedup vs baseline: 1.0804x; 1.0804x over previous
//
#include <hip/hip_runtime.h>

#define B_ 4
#define T_ 2048
#define D_ 1024
#define H_ 16
#define BT_ (B_ * T_)
#define QSCALE (0.125f * 1.44269504088896f)   // 1/sqrt(64) * log2(e), exp2-domain softmax

typedef unsigned short u16;
typedef unsigned long long u64;
typedef __attribute__((ext_vector_type(8))) __bf16 bf16x8;
typedef __attribute__((ext_vector_type(4))) float f32x4;

__device__ __forceinline__ u16 f2bf(float f) {      // f32 -> bf16 RNE
  unsigned u = __builtin_bit_cast(unsigned, f);
  u += 0x7FFFu + ((u >> 16) & 1u);
  return (u16)(u >> 16);
}

__device__ __forceinline__ void gload16(const void* g, void* l) {
  __builtin_amdgcn_global_load_lds(
      (const __attribute__((address_space(1))) void*)g,
      (__attribute__((address_space(3))) void*)l, 16, 0, 0);
}

// ---------------- fused converts: x + 4 weights + padding tile-flags ----------------
__global__ void cvt_all(const float* __restrict__ x,
                        const float* __restrict__ Wq, const float* __restrict__ Wk,
                        const float* __restrict__ Wv, const float* __restrict__ Wo,
                        u16* __restrict__ xb, u16* __restrict__ wdst,
                        const unsigned char* __restrict__ pm, unsigned char* __restrict__ fl) {
  const int fb = blockIdx.x;
  if (fb < 8192) {                                  // x: BT*D/4 float4s
    const int i = fb * 256 + threadIdx.x;
    const float4 v = ((const float4*)x)[i];
    ushort4 o;
    o.x = f2bf(v.x); o.y = f2bf(v.y); o.z = f2bf(v.z); o.w = f2bf(v.w);
    ((ushort4*)xb)[i] = o;
  } else if (fb < 12288) {                          // weights: 4 x D*D/4
    const int wsel = (fb - 8192) >> 10;
    const float* src = (wsel == 0) ? Wq : (wsel == 1) ? Wk : (wsel == 2) ? Wv : Wo;
    const int i = ((fb - 8192) & 1023) * 256 + threadIdx.x;
    const float4 v = ((const float4*)src)[i];
    ushort4 o;
    o.x = f2bf(v.x); o.y = f2bf(v.y); o.z = f2bf(v.z); o.w = f2bf(v.w);
    ((ushort4*)(wdst + (size_t)wsel * D_ * D_))[i] = o;
  } else if (threadIdx.x < 128) {                   // per-64-token padding flags
    const int i = threadIdx.x;
    const u64* p = (const u64*)(pm + i * 64);
    u64 acc = 0;
#pragma unroll
    for (int k = 0; k < 8; ++k) acc |= p[k];
    fl[i] = acc ? 1 : 0;
  }
}

// ---------------- GEMM: 128x128 tile, BK=64, 4 waves, swizzled LDS ----------------
// Proven structure (~912 TF, 2D grid, 16x16x32 MFMA -- conflict-free: 16-lane
// read phases span 16 rows -> 2-way bank aliasing = free; r19's 32x32 variant
// was a structural 4-way conflict, reverted).
// MODE 1: fused QKV -> Cq (x QSCALE), Ck, Cvt (transposed); MODE 0: out-proj.
template<int MODE>
__global__ __launch_bounds__(256, 2) void gemm_bt(
    const u16* __restrict__ A, const u16* __restrict__ Bw,
    float* __restrict__ Cf, const float* __restrict__ bias,
    const unsigned char* __restrict__ rowmask,
    u16* __restrict__ Cq, u16* __restrict__ Ck, u16* __restrict__ Cvt)
{
  __shared__ __align__(16) u16 sA[128 * 64];
  __shared__ __align__(16) u16 sB[128 * 64];
  const int tid = threadIdx.x;
  const int lane = tid & 63, wave = tid >> 6;
  const int g = lane >> 4, s15 = lane & 15;
  const int bm = blockIdx.x * 128, bn = blockIdx.y * 128;
  const int wr = wave >> 1, wc = wave & 1;

  const int srow = lane >> 3;
  const int scol = ((lane & 7) ^ srow) << 3;

  f32x4 acc[4][4] = {};

  for (int kt = 0; kt < 16; ++kt) {
    __syncthreads();
    const int k0 = kt << 6;
#pragma unroll
    for (int c = 0; c < 4; ++c) {
      const int chunk = c * 4 + wave;
      gload16(A  + (size_t)(bm + chunk * 8 + srow) * 1024 + k0 + scol, (char*)sA + chunk * 1024);
      gload16(Bw + (size_t)(bn + chunk * 8 + srow) * 1024 + k0 + scol, (char*)sB + chunk * 1024);
    }
    __syncthreads();
#pragma unroll
    for (int kk = 0; kk < 2; ++kk) {
      const int cb = ((kk << 6) | (g << 4)) ^ ((s15 & 7) << 4);
      bf16x8 af[4], bf[4];
#pragma unroll
      for (int mm = 0; mm < 4; ++mm)
        af[mm] = *(const bf16x8*)((const char*)sA + (wr * 64 + mm * 16 + s15) * 128 + cb);
#pragma unroll
      for (int nn = 0; nn < 4; ++nn)
        bf[nn] = *(const bf16x8*)((const char*)sB + (wc * 64 + nn * 16 + s15) * 128 + cb);
#pragma unroll
      for (int mm = 0; mm < 4; ++mm)
#pragma unroll
        for (int nn = 0; nn < 4; ++nn)
          acc[mm][nn] = __builtin_amdgcn_mfma_f32_16x16x32_bf16(af[mm], bf[nn], acc[mm][nn], 0, 0, 0);
    }
  }

  if (MODE == 1) {
    const int region = bn >> 10;               // 0=Q 1=K 2=V (block-uniform)
    const float a = (region == 0) ? QSCALE : 1.f;
#pragma unroll
    for (int mm = 0; mm < 4; ++mm)
#pragma unroll
      for (int nn = 0; nn < 4; ++nn) {
        const int col = bn + wc * 64 + nn * 16 + s15;
        const int colr = col & 1023;
        const int row0 = bm + wr * 64 + mm * 16 + (g << 2);
        if (region == 2) {
          ushort4 w;
          w.x = f2bf(acc[mm][nn][0]); w.y = f2bf(acc[mm][nn][1]);
          w.z = f2bf(acc[mm][nn][2]); w.w = f2bf(acc[mm][nn][3]);
          *(ushort4*)(Cvt + (size_t)colr * BT_ + row0) = w;   // V^T[d][token]
        } else {
          u16* dst = region ? Ck : Cq;
#pragma unroll
          for (int r = 0; r < 4; ++r)
            dst[(size_t)(row0 + r) * 1024 + colr] = f2bf(acc[mm][nn][r] * a);
        }
      }
  } else {
#pragma unroll
    for (int mm = 0; mm < 4; ++mm)
#pragma unroll
      for (int nn = 0; nn < 4; ++nn) {
        const int col = bn + wc * 64 + nn * 16 + s15;
        const int row0 = bm + wr * 64 + mm * 16 + (g << 2);
        const float bv = bias[col];
#pragma unroll
        for (int r = 0; r < 4; ++r) {
          float v = acc[mm][nn][r] + bv;
          v = rowmask[row0 + r] ? 0.f : v;
          Cf[(size_t)(row0 + r) * 1024 + col] = v;
        }
      }
  }
}

// ---------------- Flash attention (causal), O^T = V^T @ P^T, P in registers ----------
// (proven r15 structure: 8 waves x 16 q-rows, sequential (j,15-j) halves,
// T15 cross-tile pipeline, 4-slot KV ring, counted vmcnt, static-shift softmax)
#define QK_TILE(T, ST) do {                                                    \
  const int kvq_ = (T) << 6;                                                   \
  _Pragma("unroll")                                                            \
  for (int jf_ = 0; jf_ < 4; ++jf_) ST[jf_] = f32x4{};                         \
  if (kvq_ <= qw + 15) {                                                       \
    const u16* kbq_ = &sK[(T) & 3][0];                                         \
    _Pragma("unroll")                                                          \
    for (int ks_ = 0; ks_ < 2; ++ks_) {                                        \
      bf16x8 kf_[4];                                                           \
      _Pragma("unroll")                                                        \
      for (int jf_ = 0; jf_ < 4; ++jf_)                                        \
        kf_[jf_] = *(const bf16x8*)(kbq_ + (jf_ * 16 + s15) * 64 +             \
                                    (((ks_ * 4 + g) ^ (s15 & 7)) << 3));       \
      __builtin_amdgcn_s_setprio(1);                                           \
      _Pragma("unroll")                                                        \
      for (int jf_ = 0; jf_ < 4; ++jf_)                                        \
        ST[jf_] = __builtin_amdgcn_mfma_f32_16x16x32_bf16(kf_[jf_], qf[ks_],   \
                                                          ST[jf_], 0, 0, 0);   \
      __builtin_amdgcn_s_setprio(0);                                           \
    }                                                                          \
  }                                                                            \
} while (0)

#define ATTN_ITER(T, CUR, NXT) do {                                            \
  const int kv0_ = (T) << 6;                                                   \
  if ((T) + 3 < nt) {                                                          \
    const int s_ = ((T) + 3) & 3;                                              \
    gload16(Kb0 + (size_t)(kv0_ + 192 + srow) * D_, (char*)(&sK[s_][0]) + tid * 16); \
    gload16(Vb0 + (size_t)srow * BT_ + kv0_ + 192,  (char*)(&sV[s_][0]) + tid * 16); \
  }                                                                            \
  if ((T) + 1 < nt) QK_TILE((T) + 1, NXT);                                     \
  if (kv0_ <= qw + 15) {                                                       \
    if (kv0_ + 63 > qw) {                                                      \
      const int iq_ = qw + s15;                                                \
      _Pragma("unroll")                                                        \
      for (int jf_ = 0; jf_ < 4; ++jf_) {                                      \
        const int jb_ = kv0_ + jf_ * 16 + g * 4;                               \
        _Pragma("unroll")                                                      \
        for (int r_ = 0; r_ < 4; ++r_)                                         \
          if (jb_ + r_ > iq_) CUR[jf_][r_] = -1e30f;                           \
      }                                                                        \
    }                                                                          \
    if ((flq[(T) >> 3] >> (((T) & 7) * 8)) & 0xff) {                           \
      _Pragma("unroll")                                                        \
      for (int jf_ = 0; jf_ < 4; ++jf_) {                                      \
        const int jb_ = kv0_ + jf_ * 16 + g * 4;                               \
        uchar4 p4_ = *(const uchar4*)(pm + b * T_ + jb_);                      \
        const unsigned char* pr_ = (const unsigned char*)&p4_;                 \
        _Pragma("unroll")                                                      \
        for (int r_ = 0; r_ < 4; ++r_)                                         \
          if (pr_[r_]) CUR[jf_][r_] = -1e30f;                                  \
      }                                                                        \
    }                                                                          \
    _Pragma("unroll")                                                          \
    for (int jf_ = 0; jf_ < 4; ++jf_) {                                        \
      _Pragma("unroll")                                                        \
      for (int r_ = 0; r_ < 4; ++r_)                                           \
        CUR[jf_][r_] = __builtin_amdgcn_exp2f(CUR[jf_][r_]);                   \
      l4 += CUR[jf_];                                                          \
    }                                                                          \
    const u16* vbq_ = &sV[(T) & 3][0];                                         \
    _Pragma("unroll")                                                          \
    for (int kb_ = 0; kb_ < 2; ++kb_) {                                        \
      bf16x8 vf_[4];                                                           \
      _Pragma("unroll")                                                        \
      for (int df_ = 0; df_ < 4; ++df_)                                        \
        vf_[df_] = *(const bf16x8*)(vbq_ + (df_ * 16 + s15) * 64 +             \
                                    (((kb_ * 4 + g) ^ (s15 & 7)) << 3));       \
      unsigned w00, w01, w10, w11;                                             \
      asm("v_cvt_pk_bf16_f32 %0, %1, %2" : "=v"(w00) : "v"(CUR[2*kb_][0]),   "v"(CUR[2*kb_][1]));   \
      asm("v_cvt_pk_bf16_f32 %0, %1, %2" : "=v"(w01) : "v"(CUR[2*kb_][2]),   "v"(CUR[2*kb_][3]));   \
      asm("v_cvt_pk_bf16_f32 %0, %1, %2" : "=v"(w10) : "v"(CUR[2*kb_+1][0]), "v"(CUR[2*kb_+1][1])); \
      asm("v_cvt_pk_bf16_f32 %0, %1, %2" : "=v"(w11) : "v"(CUR[2*kb_+1][2]), "v"(CUR[2*kb_+1][3])); \
      asm("v_permlane32_swap_b32 %0, %1" : "+v"(w00), "+v"(w10));              \
      asm("v_permlane16_swap_b32 %0, %1" : "+v"(w00), "+v"(w10));              \
      asm("v_permlane32_swap_b32 %0, %1" : "+v"(w01), "+v"(w11));              \
      asm("v_permlane16_swap_b32 %0, %1" : "+v"(w01), "+v"(w11));              \
      union { unsigned u[4]; bf16x8 v; } pf_;                                  \
      pf_.u[0] = w00; pf_.u[1] = w01; pf_.u[2] = w10; pf_.u[3] = w11;          \
      __builtin_amdgcn_s_setprio(1);                                           \
      _Pragma("unroll")                                                        \
      for (int df_ = 0; df_ < 4; ++df_)                                        \
        o[df_] = __builtin_amdgcn_mfma_f32_16x16x32_bf16(vf_[df_], pf_.v,      \
                                                         o[df_], 0, 0, 0);     \
      __builtin_amdgcn_s_setprio(0);                                           \
    }                                                                          \
  }                                                                            \
  if ((T) + 1 < nt) {                                                          \
    if ((T) + 3 < nt) asm volatile("s_waitcnt vmcnt(2) lgkmcnt(0)" ::: "memory"); \
    else              asm volatile("s_waitcnt vmcnt(0) lgkmcnt(0)" ::: "memory"); \
    __builtin_amdgcn_s_barrier();                                              \
    asm volatile("" ::: "memory");                                             \
  }                                                                            \
} while (0)

__global__ __launch_bounds__(512, 4) void attn_fwd(
    const u16* __restrict__ Q, const u16* __restrict__ K,
    const u16* __restrict__ VT, const unsigned char* __restrict__ pm,
    const unsigned char* __restrict__ tileflag, u16* __restrict__ O)
{
  __shared__ __align__(16) u16 sK[4][64 * 64];   // 32 KB
  __shared__ __align__(16) u16 sV[4][64 * 64];   // 32 KB
  const int tid = threadIdx.x;
  const int lane = tid & 63, wave = tid >> 6;      // 8 waves
  const int g = lane >> 4, s15 = lane & 15;
  const int bh = blockIdx.x, b = bh >> 4, h = bh & 15;
  const int jpair = blockIdx.y;                    // 0..7
  const size_t tokbase = (size_t)b * T_;

  const int srow = tid >> 3;                       // staging: row 0..63, 16B chunk
  const int sc = (tid & 7) ^ (srow & 7);
  const u16* Kb0 = K + tokbase * D_ + h * 64 + sc * 8;
  const u16* Vb0 = VT + (size_t)(h * 64) * BT_ + tokbase + sc * 8;

  u64 flq[4];
#pragma unroll
  for (int q = 0; q < 4; ++q) flq[q] = ((const u64*)(tileflag + b * 32))[q];

#pragma unroll
  for (int half = 0; half < 2; ++half) {
    const int qt = half ? (15 - jpair) : jpair;
    const int qw = qt * 128 + wave * 16;
    const int nt = 2 * qt + 2;                     // even, >= 2

    bf16x8 qf[2];
#pragma unroll
    for (int ks = 0; ks < 2; ++ks)
      qf[ks] = *(const bf16x8*)(Q + (tokbase + qw + s15) * D_ + h * 64 + ks * 32 + g * 8);

    f32x4 o[4] = {};
    f32x4 l4 = {};

    __syncthreads();
#pragma unroll
    for (int s = 0; s < 3; ++s) {
      gload16(Kb0 + (size_t)(s * 64 + srow) * D_, (char*)(&sK[s][0]) + tid * 16);
      gload16(Vb0 + (size_t)srow * BT_ + s * 64,  (char*)(&sV[s][0]) + tid * 16);
    }
    asm volatile("s_waitcnt vmcnt(2) lgkmcnt(0)" ::: "memory");
    __builtin_amdgcn_s_barrier();
    asm volatile("" ::: "memory");

    f32x4 stA[4], stB[4];
    QK_TILE(0, stA);

    for (int t = 0; t < nt; t += 2) {
      ATTN_ITER(t, stA, stB);
      ATTN_ITER(t + 1, stB, stA);
    }

    float lv = (l4[0] + l4[1]) + (l4[2] + l4[3]);
    lv += __shfl_xor(lv, 16);
    lv += __shfl_xor(lv, 32);
    const float inv = 1.f / lv;
    u16* orow = O + (tokbase + qw + s15) * D_ + h * 64 + g * 4;
#pragma unroll
    for (int df = 0; df < 4; ++df) {
      ushort4 w;
      w.x = f2bf(o[df][0] * inv); w.y = f2bf(o[df][1] * inv);
      w.z = f2bf(o[df][2] * inv); w.w = f2bf(o[df][3] * inv);
      *(ushort4*)(orow + df * 16) = w;
    }
  }
}

// ---------------- launcher ----------------
extern "C" void kernel_launch(void* const* d_in, const int* in_sizes, int n_in,
                              void* d_out, int out_size, void* d_ws, size_t ws_size,
                              hipStream_t stream)
{
  const float* x  = (const float*)d_in[0];
  const unsigned char* pm = (const unsigned char*)d_in[1];
  const float* Wq = (const float*)d_in[2];
  const float* Wk = (const float*)d_in[3];
  const float* Wv = (const float*)d_in[4];
  const float* Wo = (const float*)d_in[5];
  const float* bo = (const float*)d_in[6];
  float* out = (float*)d_out;

  char* w = (char*)d_ws;
  u16* xb  = (u16*)w; w += (size_t)BT_ * D_ * 2;
  u16* wqb = (u16*)w; w += (size_t)D_ * D_ * 2;   // wq|wk|wv|wo contiguous
  u16* wkb = (u16*)w; w += (size_t)D_ * D_ * 2;
  u16* wvb = (u16*)w; w += (size_t)D_ * D_ * 2;
  u16* wob = (u16*)w; w += (size_t)D_ * D_ * 2;
  u16* qb  = (u16*)w; w += (size_t)BT_ * D_ * 2;
  u16* kbf = (u16*)w; w += (size_t)BT_ * D_ * 2;
  u16* vt  = (u16*)w; w += (size_t)BT_ * D_ * 2;  // V^T [1024][8192]
  u16* ao  = (u16*)w; w += (size_t)BT_ * D_ * 2;
  unsigned char* flags = (unsigned char*)w; w += 256;
  (void)wkb; (void)wvb;

  cvt_all<<<12289, 256, 0, stream>>>(x, Wq, Wk, Wv, Wo, xb, wqb, pm, flags);

  gemm_bt<1><<<dim3(64, 24), 256, 0, stream>>>(xb, wqb, nullptr, nullptr, nullptr, qb, kbf, vt);

  attn_fwd<<<dim3(B_ * H_, 8), 512, 0, stream>>>(qb, kbf, vt, pm, flags, ao);

  gemm_bt<0><<<dim3(64, 8), 256, 0, stream>>>(ao, wob, out, bo, pm, nullptr, nullptr, nullptr);
}